// Round 1
// baseline (1233.344 us; speedup 1.0000x reference)
//
#include <hip/hip_runtime.h>
#include <math.h>

#define B_    16
#define M_    128
#define T_    2048
#define H_    512
#define TOUT_ 2049

// ws layout in floats:
//  A[3][128][128] at 0        (Aq, Ak, Ao = W2*W1)
//  c[3][128]      at 49152    (W2*b1 + b2)
//  meanv[2048]    at 49536
//  q buffer       at 65536            (B*M*T = 4194304)
//  k buffer       at 65536+4194304
//  attn buffer    at 65536+2*4194304
#define A_OFF    0
#define C_OFF    49152
#define MEAN_OFF 49536
#define Q_OFF    65536
#define K_OFF    (65536 + 4194304)
#define AT_OFF   (65536 + 2 * 4194304)

// ---------------------------------------------------------------------------
// A = W2 (128x512) * W1 (512x128);  c = W2*b1 + b2
__global__ __launch_bounds__(128) void fuse_weights_kernel(
    const float* __restrict__ W1, const float* __restrict__ b1,
    const float* __restrict__ W2, const float* __restrict__ b2,
    float* __restrict__ A, float* __restrict__ c) {
  __shared__ float w2row[H_];
  int o = blockIdx.x;      // output row 0..127
  int m = threadIdx.x;     // input col 0..127
  for (int h = m; h < H_; h += 128) w2row[h] = W2[o * H_ + h];
  __syncthreads();
  float acc = 0.f;
  for (int h = 0; h < H_; ++h) acc = fmaf(w2row[h], W1[h * M_ + m], acc);
  A[o * M_ + m] = acc;
  if (m == 0) {
    float cc = b2[o];
    for (int h = 0; h < H_; ++h) cc = fmaf(w2row[h], b1[h], cc);
    c[o] = cc;
  }
}

// ---------------------------------------------------------------------------
// y[b,o,t] = leaky( sum_m A[o,m] * x[b,m,t] + c[o] )
// block: 256 thr, tile = 128 rows x 64 cols. thread: 32 rows x 1 col.
__global__ __launch_bounds__(256) void mlp_apply_kernel(
    const float* __restrict__ x, const float* __restrict__ A,
    const float* __restrict__ c, float* __restrict__ y, int ostride) {
  __shared__ float xs[128][65];  // [m][col], padded
  int b = blockIdx.y;
  int t0 = blockIdx.x * 64;
  int tid = threadIdx.x;
  int col = tid & 63;
  int obase = (tid >> 6) * 32;                       // wave-uniform
  obase = __builtin_amdgcn_readfirstlane(obase);     // force scalar A loads

  for (int i = tid; i < 128 * 64; i += 256) {
    int mm = i >> 6, cc = i & 63;
    xs[mm][cc] = x[(b * M_ + mm) * T_ + t0 + cc];
  }
  __syncthreads();

  float acc[32];
#pragma unroll
  for (int i = 0; i < 32; ++i) acc[i] = 0.f;

  for (int m = 0; m < 128; ++m) {
    float xv = xs[m][col];
    const float* Ap = A + obase * M_ + m;
#pragma unroll
    for (int i = 0; i < 32; ++i) acc[i] = fmaf(Ap[i * M_], xv, acc[i]);
  }

#pragma unroll
  for (int i = 0; i < 32; ++i) {
    int o = obase + i;
    float vv = acc[i] + c[o];
    vv = vv > 0.f ? vv : 0.01f * vv;
    y[(b * M_ + o) * ostride + t0 + col] = vv;
  }
}

// ---------------------------------------------------------------------------
// attn[b,m,q] = sum_k w[q,k]*v[b,m,k] / sum_k w[q,k]
// w[q,k] = exp(exp(qk[q,k] * (q==k ? 1-1/sqrt(T) : 1)))
// block: (b, 32 q's), all 128 m rows. Loop k in tiles of 32.
__global__ __launch_bounds__(256) void attn_kernel(
    const float* __restrict__ q, const float* __restrict__ k,
    const float* __restrict__ v, float* __restrict__ attn) {
  __shared__ float qs[128][33];
  __shared__ float ks[128][33];
  __shared__ float vs[128][33];
  __shared__ float wsm[32][33];
  __shared__ float denom[32];

  int b = blockIdx.y;
  int q0 = blockIdx.x * 32;
  int tid = threadIdx.x;

  // s-phase mapping: 2x2 tile per thread over the 32x32 score tile
  int sq = (tid & 15) * 2;
  int sk = (tid >> 4) * 2;
  // pv-phase mapping: 4 m's x 4 q's per thread
  int pq = (tid & 7) * 4;
  int pm = (tid >> 3) * 4;

  const float dm = 0.97790291f;  // 1 - 1/sqrt(2048)

  for (int i = tid; i < 128 * 32; i += 256) {
    int mm = i >> 5, qi = i & 31;
    qs[mm][qi] = q[(b * M_ + mm) * T_ + q0 + qi];
  }
  if (tid < 32) denom[tid] = 0.f;

  float num[4][4];
#pragma unroll
  for (int i = 0; i < 4; ++i)
#pragma unroll
    for (int j = 0; j < 4; ++j) num[i][j] = 0.f;

  __syncthreads();

  for (int kt = 0; kt < T_ / 32; ++kt) {
    int k0 = kt * 32;
    for (int i = tid; i < 128 * 32; i += 256) {
      int mm = i >> 5, ki = i & 31;
      int g = (b * M_ + mm) * T_ + k0 + ki;
      ks[mm][ki] = k[g];
      vs[mm][ki] = v[g];
    }
    __syncthreads();

    float s00 = 0.f, s01 = 0.f, s10 = 0.f, s11 = 0.f;
    for (int m = 0; m < 128; ++m) {
      float a0 = qs[m][sq], a1 = qs[m][sq + 1];
      float b0 = ks[m][sk], b1 = ks[m][sk + 1];
      s00 = fmaf(a0, b0, s00);
      s01 = fmaf(a0, b1, s01);
      s10 = fmaf(a1, b0, s10);
      s11 = fmaf(a1, b1, s11);
    }
    int gq = q0 + sq, gk = k0 + sk;
    float a00 = (gq == gk) ? dm : 1.f;
    float a01 = (gq == gk + 1) ? dm : 1.f;
    float a10 = (gq + 1 == gk) ? dm : 1.f;
    float a11 = (gq + 1 == gk + 1) ? dm : 1.f;
    wsm[sq][sk]         = __expf(__expf(s00 * a00));
    wsm[sq][sk + 1]     = __expf(__expf(s01 * a01));
    wsm[sq + 1][sk]     = __expf(__expf(s10 * a10));
    wsm[sq + 1][sk + 1] = __expf(__expf(s11 * a11));
    __syncthreads();

    if (tid < 32) {
      float d = 0.f;
#pragma unroll
      for (int ki = 0; ki < 32; ++ki) d += wsm[tid][ki];
      denom[tid] += d;
    }

#pragma unroll 4
    for (int ki = 0; ki < 32; ++ki) {
      float w0 = wsm[pq][ki], w1 = wsm[pq + 1][ki];
      float w2 = wsm[pq + 2][ki], w3 = wsm[pq + 3][ki];
#pragma unroll
      for (int i = 0; i < 4; ++i) {
        float vv = vs[pm + i][ki];
        num[i][0] = fmaf(vv, w0, num[i][0]);
        num[i][1] = fmaf(vv, w1, num[i][1]);
        num[i][2] = fmaf(vv, w2, num[i][2]);
        num[i][3] = fmaf(vv, w3, num[i][3]);
      }
    }
    __syncthreads();
  }

#pragma unroll
  for (int j = 0; j < 4; ++j) {
    float dinv = 1.f / denom[pq + j];
#pragma unroll
    for (int i = 0; i < 4; ++i) {
      attn[(b * M_ + pm + i) * T_ + q0 + pq + j] = num[i][j] * dinv;
    }
  }
}

// ---------------------------------------------------------------------------
// meanv[b,m] = mean(value[b,m,33:2047])   (2014 elements)
__global__ __launch_bounds__(256) void meanv_kernel(
    const float* __restrict__ v, float* __restrict__ meanv) {
  __shared__ float red[256];
  int bm = blockIdx.x;
  int tid = threadIdx.x;
  const float* row = v + (long)bm * T_;
  float s = 0.f;
  for (int i = 33 + tid; i < T_ - 1; i += 256) s += row[i];
  red[tid] = s;
  __syncthreads();
  for (int st = 128; st > 0; st >>= 1) {
    if (tid < st) red[tid] += red[tid + st];
    __syncthreads();
  }
  if (tid == 0) meanv[bm] = red[0] * (1.f / 2014.f);
}

// out[b,o,2048] = leaky( Ao * meanv[b,:] + co )
__global__ __launch_bounds__(128) void rep_ex_kernel(
    const float* __restrict__ meanv, const float* __restrict__ A,
    const float* __restrict__ c, float* __restrict__ out) {
  __shared__ float xv[128];
  int b = blockIdx.x;
  int o = threadIdx.x;
  xv[o] = meanv[b * 128 + o];
  __syncthreads();
  float acc = c[o];
  for (int m = 0; m < 128; ++m) acc = fmaf(A[o * M_ + m], xv[m], acc);
  acc = acc > 0.f ? acc : 0.01f * acc;
  out[(b * M_ + o) * TOUT_ + 2048] = acc;
}

// ---------------------------------------------------------------------------
extern "C" void kernel_launch(void* const* d_in, const int* in_sizes, int n_in,
                              void* d_out, int out_size, void* d_ws, size_t ws_size,
                              hipStream_t stream) {
  (void)in_sizes; (void)n_in; (void)out_size; (void)ws_size;
  const float* pattern = (const float*)d_in[0];
  const float* value   = (const float*)d_in[1];
  const float* Wq1 = (const float*)d_in[3];
  const float* bq1 = (const float*)d_in[4];
  const float* Wq2 = (const float*)d_in[5];
  const float* bq2 = (const float*)d_in[6];
  const float* Wk1 = (const float*)d_in[7];
  const float* bk1 = (const float*)d_in[8];
  const float* Wk2 = (const float*)d_in[9];
  const float* bk2 = (const float*)d_in[10];
  const float* Wo1 = (const float*)d_in[11];
  const float* bo1 = (const float*)d_in[12];
  const float* Wo2 = (const float*)d_in[13];
  const float* bo2 = (const float*)d_in[14];

  float* ws    = (float*)d_ws;
  float* A     = ws + A_OFF;
  float* c     = ws + C_OFF;
  float* meanv = ws + MEAN_OFF;
  float* qbuf  = ws + Q_OFF;
  float* kbuf  = ws + K_OFF;
  float* abuf  = ws + AT_OFF;
  float* out   = (float*)d_out;

  fuse_weights_kernel<<<128, 128, 0, stream>>>(Wq1, bq1, Wq2, bq2, A,         c);
  fuse_weights_kernel<<<128, 128, 0, stream>>>(Wk1, bk1, Wk2, bk2, A + 16384, c + 128);
  fuse_weights_kernel<<<128, 128, 0, stream>>>(Wo1, bo1, Wo2, bo2, A + 32768, c + 256);

  dim3 mgrid(T_ / 64, B_);
  mlp_apply_kernel<<<mgrid, 256, 0, stream>>>(pattern, A,         c,       qbuf, T_);
  mlp_apply_kernel<<<mgrid, 256, 0, stream>>>(pattern, A + 16384, c + 128, kbuf, T_);

  attn_kernel<<<dim3(T_ / 32, B_), 256, 0, stream>>>(qbuf, kbuf, value, abuf);

  mlp_apply_kernel<<<mgrid, 256, 0, stream>>>(abuf, A + 32768, c + 256, out, TOUT_);

  meanv_kernel<<<B_ * M_, 256, 0, stream>>>(value, meanv);
  rep_ex_kernel<<<B_, 128, 0, stream>>>(meanv, A + 32768, c + 256, out);
}

// Round 2
// 383.789 us; speedup vs baseline: 3.2136x; 3.2136x over previous
//
#include <hip/hip_runtime.h>
#include <math.h>

#define B_    16
#define M_    128
#define T_    2048
#define H_    512
#define TOUT_ 2049

typedef unsigned short u16;
typedef unsigned int   u32;
typedef __bf16 bf16x8 __attribute__((ext_vector_type(8)));
typedef float  f32x16 __attribute__((ext_vector_type(16)));
typedef u32    u32x4  __attribute__((ext_vector_type(4)));

// ws layout (float units):
//  A[3][128][128] @0, c[3][128] @49152, meanv @49536
//  qT bf16 [b][t][m] @65536        (4.19M u16 = 2097152 floats)
//  kT bf16 [b][t][m] @65536+2097152
//  vB bf16 [b][m][t] @65536+2*2097152
//  abuf fp32 [b][m][t] @65536+3*2097152
#define A_OFF    0
#define C_OFF    49152
#define MEAN_OFF 49536
#define QT_OFF   65536
#define KT_OFF   (65536 + 2097152)
#define VB_OFF   (65536 + 2 * 2097152)
#define AT_OFF   (65536 + 3 * 2097152)

static __device__ __forceinline__ u16 f2bf(float f) {
  u32 u = __float_as_uint(f);
  u = (u + 0x7FFFu + ((u >> 16) & 1u)) >> 16;
  return (u16)u;
}
static __device__ __forceinline__ bf16x8 ldfrag(const u16* p) {
  return __builtin_bit_cast(bf16x8, *(const u32x4*)p);
}

// ---------------------------------------------------------------------------
__global__ __launch_bounds__(128) void fuse_weights_kernel(
    const float* __restrict__ W1, const float* __restrict__ b1,
    const float* __restrict__ W2, const float* __restrict__ b2,
    float* __restrict__ A, float* __restrict__ c) {
  __shared__ float w2row[H_];
  int o = blockIdx.x;
  int m = threadIdx.x;
  for (int h = m; h < H_; h += 128) w2row[h] = W2[o * H_ + h];
  __syncthreads();
  float acc = 0.f;
  for (int h = 0; h < H_; ++h) acc = fmaf(w2row[h], W1[h * M_ + m], acc);
  A[o * M_ + m] = acc;
  if (m == 0) {
    float cc = b2[o];
    for (int h = 0; h < H_; ++h) cc = fmaf(w2row[h], b1[h], cc);
    c[o] = cc;
  }
}

// ---------------------------------------------------------------------------
// fp32 MLP apply (used for rep_in): y[b,o,t] = leaky(A x + c)
__global__ __launch_bounds__(256) void mlp_apply_kernel(
    const float* __restrict__ x, const float* __restrict__ A,
    const float* __restrict__ c, float* __restrict__ y, int ostride) {
  __shared__ float xs[128][65];
  int b = blockIdx.y;
  int t0 = blockIdx.x * 64;
  int tid = threadIdx.x;
  int col = tid & 63;
  int obase = (tid >> 6) * 32;
  obase = __builtin_amdgcn_readfirstlane(obase);

  for (int i = tid; i < 128 * 64; i += 256) {
    int mm = i >> 6, cc = i & 63;
    xs[mm][cc] = x[(b * M_ + mm) * T_ + t0 + cc];
  }
  __syncthreads();

  float acc[32];
#pragma unroll
  for (int i = 0; i < 32; ++i) acc[i] = 0.f;
  for (int m = 0; m < 128; ++m) {
    float xv = xs[m][col];
    const float* Ap = A + obase * M_ + m;
#pragma unroll
    for (int i = 0; i < 32; ++i) acc[i] = fmaf(Ap[i * M_], xv, acc[i]);
  }
#pragma unroll
  for (int i = 0; i < 32; ++i) {
    int o = obase + i;
    float vv = acc[i] + c[o];
    vv = vv > 0.f ? vv : 0.01f * vv;
    y[(b * M_ + o) * ostride + t0 + col] = vv;
  }
}

// ---------------------------------------------------------------------------
// MLP apply with bf16 TRANSPOSED output: yT[b][t][o] bf16
__global__ __launch_bounds__(256) void mlp_qk_kernel(
    const float* __restrict__ x, const float* __restrict__ A,
    const float* __restrict__ c, u16* __restrict__ yT) {
  __shared__ float xs[128][65];
  int b = blockIdx.y;
  int t0 = blockIdx.x * 64;
  int tid = threadIdx.x;
  int col = tid & 63;
  int obase = (tid >> 6) * 32;
  obase = __builtin_amdgcn_readfirstlane(obase);

  for (int i = tid; i < 128 * 64; i += 256) {
    int mm = i >> 6, cc = i & 63;
    xs[mm][cc] = x[(b * M_ + mm) * T_ + t0 + cc];
  }
  __syncthreads();

  float acc[32];
#pragma unroll
  for (int i = 0; i < 32; ++i) acc[i] = 0.f;
  for (int m = 0; m < 128; ++m) {
    float xv = xs[m][col];
    const float* Ap = A + obase * M_ + m;
#pragma unroll
    for (int i = 0; i < 32; ++i) acc[i] = fmaf(Ap[i * M_], xv, acc[i]);
  }

  u32 pk[16];
#pragma unroll
  for (int i = 0; i < 16; ++i) {
    float v0 = acc[2 * i] + c[obase + 2 * i];
    float v1 = acc[2 * i + 1] + c[obase + 2 * i + 1];
    v0 = v0 > 0.f ? v0 : 0.01f * v0;
    v1 = v1 > 0.f ? v1 : 0.01f * v1;
    pk[i] = (u32)f2bf(v0) | ((u32)f2bf(v1) << 16);
  }
  u16* dst = yT + ((size_t)(b * T_ + t0 + col)) * 128 + obase;
#pragma unroll
  for (int j = 0; j < 4; ++j) {
    u32x4 vv = {pk[4 * j], pk[4 * j + 1], pk[4 * j + 2], pk[4 * j + 3]};
    *(u32x4*)(dst + j * 8) = vv;
  }
}

// ---------------------------------------------------------------------------
// value fp32 [b][m][t] -> bf16 same layout
__global__ __launch_bounds__(256) void vcast_kernel(
    const float* __restrict__ v, u16* __restrict__ vb) {
  size_t i = ((size_t)blockIdx.x * 256 + threadIdx.x) * 8;
  float4 a = *(const float4*)&v[i];
  float4 b = *(const float4*)&v[i + 4];
  u32 p0 = (u32)f2bf(a.x) | ((u32)f2bf(a.y) << 16);
  u32 p1 = (u32)f2bf(a.z) | ((u32)f2bf(a.w) << 16);
  u32 p2 = (u32)f2bf(b.x) | ((u32)f2bf(b.y) << 16);
  u32 p3 = (u32)f2bf(b.z) | ((u32)f2bf(b.w) << 16);
  u32x4 o = {p0, p1, p2, p3};
  *(u32x4*)&vb[i] = o;
}

// ---------------------------------------------------------------------------
// MFMA attention. qT,kT: bf16 [b][t][m]; vB: bf16 [b][m][t]; out fp32 [b][m][t]
#define TQ 64
#define TK 64
#define QSTR 136  // [q|k][m] row stride (u16): 272B = 68 words == 4 mod 32
#define VSTR 72   // [m|q][k] row stride (u16): 144B = 36 words == 4 mod 32

__global__ __launch_bounds__(256, 2) void attn_mfma_kernel(
    const u16* __restrict__ qT, const u16* __restrict__ kT,
    const u16* __restrict__ vB, float* __restrict__ attn) {
  __shared__ alignas(16) u16 qs[TQ * QSTR];    // [q][m]
  __shared__ alignas(16) u16 ks[TK * QSTR];    // [k][m]
  __shared__ alignas(16) u16 vs[M_ * VSTR];    // [m][k]
  __shared__ alignas(16) u16 wsm[TQ * VSTR];   // [q][k]
  __shared__ float dls[2][TQ];

  int b = blockIdx.y;
  int q0 = blockIdx.x * TQ;
  int tid = threadIdx.x;
  int lane = tid & 63;
  int wv = tid >> 6;            // wave 0..3
  int l31 = lane & 31;
  int lh8 = (lane >> 5) * 8;    // k-of-mfma sub-offset

  // ---- stage Q tile [64 q][128 m]
  {
    const u16* gq = qT + ((size_t)(b * T_ + q0)) * 128;
    for (int it = 0; it < 4; ++it) {
      int r = it * 16 + (tid >> 4);
      int cm = (tid & 15) * 8;
      *(u32x4*)&qs[r * QSTR + cm] = *(const u32x4*)&gq[r * 128 + cm];
    }
  }
  __syncthreads();

  // persistent Q A-frags: wave owns q rows qw..qw+31
  int qw = (wv >> 1) * 32;   // S-phase q-half
  int kw = (wv & 1) * 32;    // S-phase k-half
  bf16x8 afrag[8];
  {
    const u16* qrow = &qs[(qw + l31) * QSTR + lh8];
#pragma unroll
    for (int s = 0; s < 8; ++s) afrag[s] = ldfrag(qrow + s * 16);
  }

  int qt = wv & 1;           // PV q-tile
  int mb = (wv >> 1) * 2;    // PV m-tile base (2 tiles of 32)

  f32x16 pacc[2];
  float dreg[16];
#pragma unroll
  for (int i = 0; i < 16; ++i) { pacc[0][i] = 0.f; pacc[1][i] = 0.f; dreg[i] = 0.f; }

  for (int kt = 0; kt < T_ / TK; ++kt) {
    int k0 = kt * TK;
    __syncthreads();  // previous PV reads done
    // ---- stage K [64 k][128 m] and V [128 m][64 k]
    {
      const u16* gk = kT + ((size_t)(b * T_ + k0)) * 128;
      for (int it = 0; it < 4; ++it) {
        int r = it * 16 + (tid >> 4);
        int cm = (tid & 15) * 8;
        *(u32x4*)&ks[r * QSTR + cm] = *(const u32x4*)&gk[r * 128 + cm];
      }
      const u16* gv = vB + (size_t)b * M_ * T_ + k0;
      for (int it = 0; it < 4; ++it) {
        int m = it * 32 + (tid >> 3);
        int ck = (tid & 7) * 8;
        *(u32x4*)&vs[m * VSTR + ck] = *(const u32x4*)&gv[(size_t)m * T_ + ck];
      }
    }
    __syncthreads();

    // ---- S = Q^T K  (32q x 32k per wave), inner m=128 in 8 steps
    f32x16 sacc;
#pragma unroll
    for (int i = 0; i < 16; ++i) sacc[i] = 0.f;
    {
      const u16* krow = &ks[(kw + l31) * QSTR + lh8];
#pragma unroll
      for (int s = 0; s < 8; ++s) {
        bf16x8 bf = ldfrag(krow + s * 16);
        sacc = __builtin_amdgcn_mfma_f32_32x32x16_bf16(afrag[s], bf, sacc, 0, 0, 0);
      }
    }

    // ---- w = exp(exp(s * diag_adj)), bf16-round, store wsm, accumulate den
    bool dtile = (k0 == q0);
    int kl = kw + l31;
#pragma unroll
    for (int r = 0; r < 16; ++r) {
      int qrow = qw + (r & 3) + 8 * (r >> 2) + 4 * (lane >> 5);
      float s = sacc[r];
      if (dtile && (qrow == kl)) s *= 0.97790291f;  // 1 - 1/sqrt(2048)
      float w = __expf(__expf(s));
      u16 wb = f2bf(w);
      dreg[r] += __uint_as_float((u32)wb << 16);
      wsm[qrow * VSTR + kl] = wb;
    }
    __syncthreads();

    // ---- PV: D[m,q] += V W^T   (2 m-tiles x 1 q-tile per wave)
#pragma unroll
    for (int s2 = 0; s2 < 4; ++s2) {
      bf16x8 wf = ldfrag(&wsm[(qt * 32 + l31) * VSTR + s2 * 16 + lh8]);
#pragma unroll
      for (int mi = 0; mi < 2; ++mi) {
        bf16x8 vf = ldfrag(&vs[((mb + mi) * 32 + l31) * VSTR + s2 * 16 + lh8]);
        pacc[mi] = __builtin_amdgcn_mfma_f32_32x32x16_bf16(vf, wf, pacc[mi], 0, 0, 0);
      }
    }
  }

  // ---- denominator wave-reduce (across the 32 k-lanes of each half-wave)
#pragma unroll
  for (int r = 0; r < 16; ++r) {
    float d = dreg[r];
    for (int off = 1; off < 32; off <<= 1) d += __shfl_xor(d, off, 64);
    dreg[r] = d;
  }
  if (l31 == 0) {
#pragma unroll
    for (int r = 0; r < 16; ++r) {
      int qrow = qw + (r & 3) + 8 * (r >> 2) + 4 * (lane >> 5);
      dls[wv & 1][qrow] = dreg[r];
    }
  }
  __syncthreads();

  float rden = 1.f / (dls[0][qt * 32 + l31] + dls[1][qt * 32 + l31]);
#pragma unroll
  for (int mi = 0; mi < 2; ++mi) {
#pragma unroll
    for (int r = 0; r < 16; ++r) {
      int m = (mb + mi) * 32 + (r & 3) + 8 * (r >> 2) + 4 * (lane >> 5);
      attn[((size_t)(b * M_ + m)) * T_ + q0 + qt * 32 + l31] = pacc[mi][r] * rden;
    }
  }
}

// ---------------------------------------------------------------------------
__global__ __launch_bounds__(256) void meanv_kernel(
    const float* __restrict__ v, float* __restrict__ meanv) {
  __shared__ float red[256];
  int bm = blockIdx.x;
  int tid = threadIdx.x;
  const float* row = v + (size_t)bm * T_;
  float s = 0.f;
  for (int i = 33 + tid; i < T_ - 1; i += 256) s += row[i];
  red[tid] = s;
  __syncthreads();
  for (int st = 128; st > 0; st >>= 1) {
    if (tid < st) red[tid] += red[tid + st];
    __syncthreads();
  }
  if (tid == 0) meanv[bm] = red[0] * (1.f / 2014.f);
}

__global__ __launch_bounds__(128) void rep_ex_kernel(
    const float* __restrict__ meanv, const float* __restrict__ A,
    const float* __restrict__ c, float* __restrict__ out) {
  __shared__ float xv[128];
  int b = blockIdx.x;
  int o = threadIdx.x;
  xv[o] = meanv[b * 128 + o];
  __syncthreads();
  float acc = c[o];
  for (int m = 0; m < 128; ++m) acc = fmaf(A[o * M_ + m], xv[m], acc);
  acc = acc > 0.f ? acc : 0.01f * acc;
  out[(b * M_ + o) * TOUT_ + 2048] = acc;
}

// ---------------------------------------------------------------------------
extern "C" void kernel_launch(void* const* d_in, const int* in_sizes, int n_in,
                              void* d_out, int out_size, void* d_ws, size_t ws_size,
                              hipStream_t stream) {
  (void)in_sizes; (void)n_in; (void)out_size; (void)ws_size;
  const float* pattern = (const float*)d_in[0];
  const float* value   = (const float*)d_in[1];
  const float* Wq1 = (const float*)d_in[3];
  const float* bq1 = (const float*)d_in[4];
  const float* Wq2 = (const float*)d_in[5];
  const float* bq2 = (const float*)d_in[6];
  const float* Wk1 = (const float*)d_in[7];
  const float* bk1 = (const float*)d_in[8];
  const float* Wk2 = (const float*)d_in[9];
  const float* bk2 = (const float*)d_in[10];
  const float* Wo1 = (const float*)d_in[11];
  const float* bo1 = (const float*)d_in[12];
  const float* Wo2 = (const float*)d_in[13];
  const float* bo2 = (const float*)d_in[14];

  float* ws    = (float*)d_ws;
  float* A     = ws + A_OFF;
  float* c     = ws + C_OFF;
  float* meanv = ws + MEAN_OFF;
  u16*   qT    = (u16*)(ws + QT_OFF);
  u16*   kT    = (u16*)(ws + KT_OFF);
  u16*   vB    = (u16*)(ws + VB_OFF);
  float* abuf  = ws + AT_OFF;
  float* out   = (float*)d_out;

  fuse_weights_kernel<<<128, 128, 0, stream>>>(Wq1, bq1, Wq2, bq2, A,         c);
  fuse_weights_kernel<<<128, 128, 0, stream>>>(Wk1, bk1, Wk2, bk2, A + 16384, c + 128);
  fuse_weights_kernel<<<128, 128, 0, stream>>>(Wo1, bo1, Wo2, bo2, A + 32768, c + 256);

  dim3 mgrid(T_ / 64, B_);
  mlp_qk_kernel<<<mgrid, 256, 0, stream>>>(pattern, A,         c,       qT);
  mlp_qk_kernel<<<mgrid, 256, 0, stream>>>(pattern, A + 16384, c + 128, kT);
  vcast_kernel<<<(B_ * M_ * T_) / (256 * 8), 256, 0, stream>>>(value, vB);

  attn_mfma_kernel<<<dim3(T_ / TQ, B_), 256, 0, stream>>>(qT, kT, vB, abuf);

  mlp_apply_kernel<<<mgrid, 256, 0, stream>>>(abuf, A + 32768, c + 256, out, TOUT_);

  meanv_kernel<<<B_ * M_, 256, 0, stream>>>(value, meanv);
  rep_ex_kernel<<<B_, 128, 0, stream>>>(meanv, A + 32768, c + 256, out);
}

// Round 3
// 207.822 us; speedup vs baseline: 5.9346x; 1.8467x over previous
//
#include <hip/hip_runtime.h>
#include <math.h>

#define B_    16
#define M_    128
#define T_    2048
#define H_    512
#define TOUT_ 2049

typedef unsigned short u16;
typedef unsigned int   u32;
typedef __bf16 bf16x8 __attribute__((ext_vector_type(8)));
typedef float  f32x16 __attribute__((ext_vector_type(16)));
typedef u32    u32x4  __attribute__((ext_vector_type(4)));
typedef u32    u32x2  __attribute__((ext_vector_type(2)));

// ws layout (float units):
//  A[3][128][128] @0, c[3][128] @49152, meanv @49536
//  Aqk_bf u16[256][128] @51584 (16384 fl), Ao_bf u16[128][128] @67968 (8192 fl)
//  qT bf16 [b][t][128] @76160, kT @+2097152, vB bf16 [b][m][t] @+2*2097152
#define A_OFF     0
#define C_OFF     49152
#define MEAN_OFF  49536
#define AQKBF_OFF 51584
#define AOBF_OFF  67968
#define QT_OFF    76160
#define KT_OFF    (76160 + 2097152)
#define VB_OFF    (76160 + 2 * 2097152)

static __device__ __forceinline__ u16 f2bf(float f) {
  u32 u = __float_as_uint(f);
  u = (u + 0x7FFFu + ((u >> 16) & 1u)) >> 16;
  return (u16)u;
}
static __device__ __forceinline__ u32 pk2(float lo, float hi) {
  return (u32)f2bf(lo) | ((u32)f2bf(hi) << 16);
}
static __device__ __forceinline__ bf16x8 ldfrag(const u16* p) {
  return __builtin_bit_cast(bf16x8, *(const u32x4*)p);
}

// ---------------------------------------------------------------------------
// one launch for q/k/o weight fusion; also emits bf16 copies
__global__ __launch_bounds__(128) void fuse_weights_all(
    const float* __restrict__ W1q, const float* __restrict__ b1q,
    const float* __restrict__ W2q, const float* __restrict__ b2q,
    const float* __restrict__ W1k, const float* __restrict__ b1k,
    const float* __restrict__ W2k, const float* __restrict__ b2k,
    const float* __restrict__ W1o, const float* __restrict__ b1o,
    const float* __restrict__ W2o, const float* __restrict__ b2o,
    float* __restrict__ A, float* __restrict__ c,
    u16* __restrict__ Aqk_bf, u16* __restrict__ Ao_bf) {
  __shared__ float w2row[H_];
  int which = blockIdx.x >> 7;
  int o = blockIdx.x & 127;
  const float* W1 = which == 0 ? W1q : which == 1 ? W1k : W1o;
  const float* b1 = which == 0 ? b1q : which == 1 ? b1k : b1o;
  const float* W2 = which == 0 ? W2q : which == 1 ? W2k : W2o;
  const float* b2 = which == 0 ? b2q : which == 1 ? b2k : b2o;
  int m = threadIdx.x;
  for (int h = m; h < H_; h += 128) w2row[h] = W2[o * H_ + h];
  __syncthreads();
  float acc = 0.f;
  for (int h = 0; h < H_; ++h) acc = fmaf(w2row[h], W1[h * M_ + m], acc);
  A[which * 16384 + o * M_ + m] = acc;
  u16 ab = f2bf(acc);
  if (which == 0)      Aqk_bf[o * 128 + m] = ab;
  else if (which == 1) Aqk_bf[(128 + o) * 128 + m] = ab;
  else                 Ao_bf[o * 128 + m] = ab;
  if (m == 0) {
    float cc = b2[o];
    for (int h = 0; h < H_; ++h) cc = fmaf(w2row[h], b1[h], cc);
    c[which * 128 + o] = cc;
  }
}

// ---------------------------------------------------------------------------
// q and k MLPs in one MFMA kernel. out: qT/kT bf16 [b][t][128]
#define XSTR 136  // u16 stride, 68 words == 4 mod 32 (measured conflict-free)

__global__ __launch_bounds__(256) void mlp_qk_fused(
    const float* __restrict__ pattern, const u16* __restrict__ Aqk_bf,
    const float* __restrict__ cqk, u16* __restrict__ qT, u16* __restrict__ kT) {
  __shared__ alignas(16) u16 xs[64 * XSTR];  // [t][m] bf16, transposed pattern
  int b = blockIdx.y;
  int t0 = blockIdx.x * 64;
  int tid = threadIdx.x;
  int lane = tid & 63;
  int wv = tid >> 6;
  int l31 = lane & 31;
  int lh8 = (lane >> 5) * 8;

  // preload A-frags: wave handles o-tiles {2wv, 2wv+1} (o in [0,256))
  bf16x8 afr[2][8];
#pragma unroll
  for (int i = 0; i < 2; ++i) {
    const u16* ap = Aqk_bf + ((2 * wv + i) * 32 + l31) * 128 + lh8;
#pragma unroll
    for (int s = 0; s < 8; ++s) afr[i][s] = ldfrag(ap + 16 * s);
  }

  // stage pattern transposed: thread = (m-pair mp = lane, t-chunk = wave)
  {
    int mp = tid & 63;
    int tc = tid >> 6;
    const float* r0 = pattern + ((size_t)(b * M_ + 2 * mp)) * T_ + t0 + tc * 16;
    const float* r1 = r0 + T_;
    u32* xw = (u32*)xs;
#pragma unroll
    for (int j = 0; j < 4; ++j) {
      float4 a = *(const float4*)(r0 + 4 * j);
      float4 bb = *(const float4*)(r1 + 4 * j);
      int tt = tc * 16 + 4 * j;
      xw[(tt + 0) * 68 + mp] = pk2(a.x, bb.x);
      xw[(tt + 1) * 68 + mp] = pk2(a.y, bb.y);
      xw[(tt + 2) * 68 + mp] = pk2(a.z, bb.z);
      xw[(tt + 3) * 68 + mp] = pk2(a.w, bb.w);
    }
  }
  __syncthreads();

#pragma unroll
  for (int tt = 0; tt < 2; ++tt) {
    bf16x8 bfr[8];
    const u16* bp = &xs[(tt * 32 + l31) * XSTR + lh8];
#pragma unroll
    for (int s = 0; s < 8; ++s) bfr[s] = ldfrag(bp + 16 * s);
#pragma unroll
    for (int i = 0; i < 2; ++i) {
      f32x16 acc;
#pragma unroll
      for (int r = 0; r < 16; ++r) acc[r] = 0.f;
#pragma unroll
      for (int s = 0; s < 8; ++s)
        acc = __builtin_amdgcn_mfma_f32_32x32x16_bf16(afr[i][s], bfr[s], acc, 0, 0, 0);
      // D[o][t]: col = t (lane&31), row = o
      int ot = 2 * wv + i;
      u16* dst = (ot < 4) ? qT : kT;
      int ob = (ot & 3) * 32;
      size_t trow = ((size_t)(b * T_ + t0 + tt * 32 + l31)) * 128;
#pragma unroll
      for (int g = 0; g < 4; ++g) {
        int o0 = 8 * g + 4 * (lane >> 5);
        float v0 = acc[4 * g + 0] + cqk[ot * 32 + o0 + 0];
        float v1 = acc[4 * g + 1] + cqk[ot * 32 + o0 + 1];
        float v2 = acc[4 * g + 2] + cqk[ot * 32 + o0 + 2];
        float v3 = acc[4 * g + 3] + cqk[ot * 32 + o0 + 3];
        v0 = v0 > 0.f ? v0 : 0.01f * v0;
        v1 = v1 > 0.f ? v1 : 0.01f * v1;
        v2 = v2 > 0.f ? v2 : 0.01f * v2;
        v3 = v3 > 0.f ? v3 : 0.01f * v3;
        u32x2 w = {pk2(v0, v1), pk2(v2, v3)};
        *(u32x2*)(dst + trow + ob + o0) = w;
      }
    }
  }
}

// ---------------------------------------------------------------------------
// value cast to bf16 + windowed row mean, one pass
__global__ __launch_bounds__(256) void vcast_mean(
    const float* __restrict__ v, u16* __restrict__ vb, float* __restrict__ meanv) {
  __shared__ float red[256];
  int bm = blockIdx.x;
  int tid = threadIdx.x;
  const float* row = v + (size_t)bm * T_;
  int i0 = tid * 8;
  float4 a = *(const float4*)(row + i0);
  float4 bq = *(const float4*)(row + i0 + 4);
  u32x4 o = {pk2(a.x, a.y), pk2(a.z, a.w), pk2(bq.x, bq.y), pk2(bq.z, bq.w)};
  *(u32x4*)&vb[(size_t)bm * T_ + i0] = o;
  float vals[8] = {a.x, a.y, a.z, a.w, bq.x, bq.y, bq.z, bq.w};
  float s = 0.f;
#pragma unroll
  for (int j = 0; j < 8; ++j) {
    int idx = i0 + j;
    if (idx >= 33 && idx < T_ - 1) s += vals[j];
  }
  red[tid] = s;
  __syncthreads();
  for (int st = 128; st > 0; st >>= 1) {
    if (tid < st) red[tid] += red[tid + st];
    __syncthreads();
  }
  if (tid == 0) meanv[bm] = red[0] * (1.f / 2014.f);
}

// ---------------------------------------------------------------------------
// MFMA attention + fused o-MLP epilogue. Writes out fp32 [b][o][2049].
#define TQ 64
#define TK 64
#define QSTR 136  // u16: 68 words == 4 mod 32
#define VSTR 72   // u16: 36 words == 4 mod 32

__global__ __launch_bounds__(256, 2) void attn_mfma_kernel(
    const u16* __restrict__ qT, const u16* __restrict__ kT,
    const u16* __restrict__ vB, const u16* __restrict__ Ao_bf,
    const float* __restrict__ co, float* __restrict__ out) {
  __shared__ alignas(16) u16 qs[TQ * QSTR];    // [q][m]; reused as P^T [q][m]
  __shared__ alignas(16) u16 ks[TK * QSTR];    // [k][m]
  __shared__ alignas(16) u16 vs[M_ * VSTR];    // [m][k]
  __shared__ alignas(16) u16 wsm[TQ * VSTR];   // [q][k]
  __shared__ float dls[2][TQ];

  int b = blockIdx.y;
  int q0 = blockIdx.x * TQ;
  int tid = threadIdx.x;
  int lane = tid & 63;
  int wv = tid >> 6;
  int l31 = lane & 31;
  int lh8 = (lane >> 5) * 8;

  // stage Q tile [64 q][128 m]
  {
    const u16* gq = qT + ((size_t)(b * T_ + q0)) * 128;
    for (int it = 0; it < 4; ++it) {
      int r = it * 16 + (tid >> 4);
      int cm = (tid & 15) * 8;
      *(u32x4*)&qs[r * QSTR + cm] = *(const u32x4*)&gq[r * 128 + cm];
    }
  }
  // preload Ao A-frags: wave wv owns o rows wv*32..+31
  bf16x8 aofr[8];
  {
    const u16* ap = Ao_bf + (wv * 32 + l31) * 128 + lh8;
#pragma unroll
    for (int s = 0; s < 8; ++s) aofr[s] = ldfrag(ap + 16 * s);
  }
  __syncthreads();

  int qw = (wv >> 1) * 32;   // S-phase q-half
  int kw = (wv & 1) * 32;    // S-phase k-half
  bf16x8 afrag[8];
  {
    const u16* qrow = &qs[(qw + l31) * QSTR + lh8];
#pragma unroll
    for (int s = 0; s < 8; ++s) afrag[s] = ldfrag(qrow + s * 16);
  }

  int qt = wv & 1;           // PV q-tile
  int mb = (wv >> 1) * 2;    // PV m-tile base

  f32x16 pacc[2];
  float dreg[16];
#pragma unroll
  for (int i = 0; i < 16; ++i) { pacc[0][i] = 0.f; pacc[1][i] = 0.f; dreg[i] = 0.f; }

  for (int kt = 0; kt < T_ / TK; ++kt) {
    int k0 = kt * TK;
    __syncthreads();
    {
      const u16* gk = kT + ((size_t)(b * T_ + k0)) * 128;
      for (int it = 0; it < 4; ++it) {
        int r = it * 16 + (tid >> 4);
        int cm = (tid & 15) * 8;
        *(u32x4*)&ks[r * QSTR + cm] = *(const u32x4*)&gk[r * 128 + cm];
      }
      const u16* gv = vB + (size_t)b * M_ * T_ + k0;
      for (int it = 0; it < 4; ++it) {
        int m = it * 32 + (tid >> 3);
        int ck = (tid & 7) * 8;
        *(u32x4*)&vs[m * VSTR + ck] = *(const u32x4*)&gv[(size_t)m * T_ + ck];
      }
    }
    __syncthreads();

    // S = Q^T K
    f32x16 sacc;
#pragma unroll
    for (int i = 0; i < 16; ++i) sacc[i] = 0.f;
    {
      const u16* krow = &ks[(kw + l31) * QSTR + lh8];
#pragma unroll
      for (int s = 0; s < 8; ++s) {
        bf16x8 bf = ldfrag(krow + s * 16);
        sacc = __builtin_amdgcn_mfma_f32_32x32x16_bf16(afrag[s], bf, sacc, 0, 0, 0);
      }
    }

    // w = exp(exp(s)), diag-adjusted only on the diagonal tile (uniform branch)
    int kl = kw + l31;
    if (k0 == q0) {
#pragma unroll
      for (int r = 0; r < 16; ++r) {
        int qrow = qw + (r & 3) + 8 * (r >> 2) + 4 * (lane >> 5);
        if (qrow == kl) sacc[r] *= 0.97790291f;  // 1 - 1/sqrt(2048)
      }
    }
#pragma unroll
    for (int r = 0; r < 16; ++r) {
      int qrow = qw + (r & 3) + 8 * (r >> 2) + 4 * (lane >> 5);
      float w = __expf(__expf(sacc[r]));
      u16 wb = f2bf(w);
      dreg[r] += __uint_as_float((u32)wb << 16);
      wsm[qrow * VSTR + kl] = wb;
    }
    __syncthreads();

    // PV: D[m][q] += V W^T
#pragma unroll
    for (int s2 = 0; s2 < 4; ++s2) {
      bf16x8 wf = ldfrag(&wsm[(qt * 32 + l31) * VSTR + s2 * 16 + lh8]);
#pragma unroll
      for (int mi = 0; mi < 2; ++mi) {
        bf16x8 vf = ldfrag(&vs[((mb + mi) * 32 + l31) * VSTR + s2 * 16 + lh8]);
        pacc[mi] = __builtin_amdgcn_mfma_f32_32x32x16_bf16(vf, wf, pacc[mi], 0, 0, 0);
      }
    }
  }

  // denominator reduce
#pragma unroll
  for (int r = 0; r < 16; ++r) {
    float d = dreg[r];
    for (int off = 1; off < 32; off <<= 1) d += __shfl_xor(d, off, 64);
    dreg[r] = d;
  }
  if (l31 == 0) {
#pragma unroll
    for (int r = 0; r < 16; ++r) {
      int qrow = qw + (r & 3) + 8 * (r >> 2) + 4 * (lane >> 5);
      dls[wv & 1][qrow] = dreg[r];
    }
  }
  __syncthreads();

  // write P^T = (num/den) bf16 into qs as [q][m]
  {
    int qcol = qt * 32 + l31;
    float rden = 1.f / (dls[0][qcol] + dls[1][qcol]);
#pragma unroll
    for (int mi = 0; mi < 2; ++mi) {
      int mbase = (mb + mi) * 32 + 4 * (lane >> 5);
#pragma unroll
      for (int g = 0; g < 4; ++g) {
        float v0 = pacc[mi][4 * g + 0] * rden;
        float v1 = pacc[mi][4 * g + 1] * rden;
        float v2 = pacc[mi][4 * g + 2] * rden;
        float v3 = pacc[mi][4 * g + 3] * rden;
        u32x2 w = {pk2(v0, v1), pk2(v2, v3)};
        *(u32x2*)&qs[qcol * QSTR + mbase + 8 * g] = w;
      }
    }
  }
  __syncthreads();

  // o-MLP: out[o][q] = leaky(sum_m Ao[o][m] * P[m][q] + co[o])
#pragma unroll
  for (int qt2 = 0; qt2 < 2; ++qt2) {
    bf16x8 pfr[8];
    const u16* pp = &qs[(qt2 * 32 + l31) * QSTR + lh8];
#pragma unroll
    for (int s = 0; s < 8; ++s) pfr[s] = ldfrag(pp + 16 * s);
    f32x16 oacc;
#pragma unroll
    for (int r = 0; r < 16; ++r) oacc[r] = 0.f;
#pragma unroll
    for (int s = 0; s < 8; ++s)
      oacc = __builtin_amdgcn_mfma_f32_32x32x16_bf16(aofr[s], pfr[s], oacc, 0, 0, 0);
#pragma unroll
    for (int r = 0; r < 16; ++r) {
      int orow = wv * 32 + (r & 3) + 8 * (r >> 2) + 4 * (lane >> 5);
      float v = oacc[r] + co[orow];
      v = v > 0.f ? v : 0.01f * v;
      out[((size_t)(b * M_ + orow)) * TOUT_ + q0 + qt2 * 32 + l31] = v;
    }
  }
}

// ---------------------------------------------------------------------------
__global__ __launch_bounds__(128) void rep_ex_kernel(
    const float* __restrict__ meanv, const float* __restrict__ A,
    const float* __restrict__ c, float* __restrict__ out) {
  __shared__ float xv[128];
  int b = blockIdx.x;
  int o = threadIdx.x;
  xv[o] = meanv[b * 128 + o];
  __syncthreads();
  float acc = c[o];
  for (int m = 0; m < 128; ++m) acc = fmaf(A[o * M_ + m], xv[m], acc);
  acc = acc > 0.f ? acc : 0.01f * acc;
  out[(b * M_ + o) * TOUT_ + 2048] = acc;
}

// ---------------------------------------------------------------------------
extern "C" void kernel_launch(void* const* d_in, const int* in_sizes, int n_in,
                              void* d_out, int out_size, void* d_ws, size_t ws_size,
                              hipStream_t stream) {
  (void)in_sizes; (void)n_in; (void)out_size; (void)ws_size;
  const float* pattern = (const float*)d_in[0];
  const float* value   = (const float*)d_in[1];
  const float* Wq1 = (const float*)d_in[3];
  const float* bq1 = (const float*)d_in[4];
  const float* Wq2 = (const float*)d_in[5];
  const float* bq2 = (const float*)d_in[6];
  const float* Wk1 = (const float*)d_in[7];
  const float* bk1 = (const float*)d_in[8];
  const float* Wk2 = (const float*)d_in[9];
  const float* bk2 = (const float*)d_in[10];
  const float* Wo1 = (const float*)d_in[11];
  const float* bo1 = (const float*)d_in[12];
  const float* Wo2 = (const float*)d_in[13];
  const float* bo2 = (const float*)d_in[14];

  float* ws     = (float*)d_ws;
  float* A      = ws + A_OFF;
  float* c      = ws + C_OFF;
  float* meanv  = ws + MEAN_OFF;
  u16*   Aqk_bf = (u16*)(ws + AQKBF_OFF);
  u16*   Ao_bf  = (u16*)(ws + AOBF_OFF);
  u16*   qT     = (u16*)(ws + QT_OFF);
  u16*   kT     = (u16*)(ws + KT_OFF);
  u16*   vB     = (u16*)(ws + VB_OFF);
  float* out    = (float*)d_out;

  fuse_weights_all<<<384, 128, 0, stream>>>(
      Wq1, bq1, Wq2, bq2, Wk1, bk1, Wk2, bk2, Wo1, bo1, Wo2, bo2,
      A, c, Aqk_bf, Ao_bf);

  mlp_qk_fused<<<dim3(T_ / 64, B_), 256, 0, stream>>>(pattern, Aqk_bf, c, qT, kT);
  vcast_mean<<<B_ * M_, 256, 0, stream>>>(value, vB, meanv);

  attn_mfma_kernel<<<dim3(T_ / TQ, B_), 256, 0, stream>>>(
      qT, kT, vB, Ao_bf, c + 256, out);

  rep_ex_kernel<<<B_, 128, 0, stream>>>(meanv, A + 32768, c + 256, out);
}

// Round 4
// 202.689 us; speedup vs baseline: 6.0849x; 1.0253x over previous
//
#include <hip/hip_runtime.h>
#include <math.h>

#define B_    16
#define M_    128
#define T_    2048
#define H_    512
#define TOUT_ 2049

typedef unsigned short u16;
typedef unsigned int   u32;
typedef __bf16 bf16x8 __attribute__((ext_vector_type(8)));
typedef float  f32x16 __attribute__((ext_vector_type(16)));
typedef u32    u32x4  __attribute__((ext_vector_type(4)));
typedef u32    u32x2  __attribute__((ext_vector_type(2)));

// ws layout (float units)
#define A_OFF     0
#define C_OFF     49152
#define MEAN_OFF  49536
#define AQKBF_OFF 51584
#define AOBF_OFF  67968
#define QT_OFF    76160
#define KT_OFF    (76160 + 2097152)
#define VB_OFF    (76160 + 2 * 2097152)

static __device__ __forceinline__ u16 f2bf(float f) {
  u32 u = __float_as_uint(f);
  u = (u + 0x7FFFu + ((u >> 16) & 1u)) >> 16;
  return (u16)u;
}
static __device__ __forceinline__ u32 pk2(float lo, float hi) {
  return (u32)f2bf(lo) | ((u32)f2bf(hi) << 16);
}
static __device__ __forceinline__ bf16x8 ldfrag(const u16* p) {
  return __builtin_bit_cast(bf16x8, *(const u32x4*)p);
}

// ---------------------------------------------------------------------------
__global__ __launch_bounds__(128) void fuse_weights_all(
    const float* __restrict__ W1q, const float* __restrict__ b1q,
    const float* __restrict__ W2q, const float* __restrict__ b2q,
    const float* __restrict__ W1k, const float* __restrict__ b1k,
    const float* __restrict__ W2k, const float* __restrict__ b2k,
    const float* __restrict__ W1o, const float* __restrict__ b1o,
    const float* __restrict__ W2o, const float* __restrict__ b2o,
    float* __restrict__ A, float* __restrict__ c,
    u16* __restrict__ Aqk_bf, u16* __restrict__ Ao_bf) {
  __shared__ float w2row[H_];
  int which = blockIdx.x >> 7;
  int o = blockIdx.x & 127;
  const float* W1 = which == 0 ? W1q : which == 1 ? W1k : W1o;
  const float* b1 = which == 0 ? b1q : which == 1 ? b1k : b1o;
  const float* W2 = which == 0 ? W2q : which == 1 ? W2k : W2o;
  const float* b2 = which == 0 ? b2q : which == 1 ? b2k : b2o;
  int m = threadIdx.x;
  for (int h = m; h < H_; h += 128) w2row[h] = W2[o * H_ + h];
  __syncthreads();
  float acc = 0.f;
  for (int h = 0; h < H_; ++h) acc = fmaf(w2row[h], W1[h * M_ + m], acc);
  A[which * 16384 + o * M_ + m] = acc;
  u16 ab = f2bf(acc);
  if (which == 0)      Aqk_bf[o * 128 + m] = ab;
  else if (which == 1) Aqk_bf[(128 + o) * 128 + m] = ab;
  else                 Ao_bf[o * 128 + m] = ab;
  if (m == 0) {
    float cc = b2[o];
    for (int h = 0; h < H_; ++h) cc = fmaf(w2row[h], b1[h], cc);
    c[which * 128 + o] = cc;
  }
}

// ---------------------------------------------------------------------------
// prep: blocks [0,512) = q/k MLP (MFMA); blocks [512,2560) = value cast+mean
#define XSTR 136

__global__ __launch_bounds__(256) void prep_kernel(
    const float* __restrict__ pattern, const u16* __restrict__ Aqk_bf,
    const float* __restrict__ cqk, u16* __restrict__ qT, u16* __restrict__ kT,
    const float* __restrict__ value, u16* __restrict__ vb,
    float* __restrict__ meanv) {
  __shared__ alignas(16) u16 sxs[64 * XSTR];
  int bx = blockIdx.x;
  int tid = threadIdx.x;

  if (bx >= 512) {
    // ---- value cast + windowed mean
    int bm = bx - 512;
    float* red = (float*)sxs;
    const float* row = value + (size_t)bm * T_;
    int i0 = tid * 8;
    float4 a = *(const float4*)(row + i0);
    float4 bq = *(const float4*)(row + i0 + 4);
    u32x4 o = {pk2(a.x, a.y), pk2(a.z, a.w), pk2(bq.x, bq.y), pk2(bq.z, bq.w)};
    *(u32x4*)&vb[(size_t)bm * T_ + i0] = o;
    float vals[8] = {a.x, a.y, a.z, a.w, bq.x, bq.y, bq.z, bq.w};
    float s = 0.f;
#pragma unroll
    for (int j = 0; j < 8; ++j) {
      int idx = i0 + j;
      if (idx >= 33 && idx < T_ - 1) s += vals[j];
    }
    red[tid] = s;
    __syncthreads();
    for (int st = 128; st > 0; st >>= 1) {
      if (tid < st) red[tid] += red[tid + st];
      __syncthreads();
    }
    if (tid == 0) meanv[bm] = red[0] * (1.f / 2014.f);
    return;
  }

  // ---- q/k MLP via MFMA
  int b = bx >> 5;
  int t0 = (bx & 31) * 64;
  int lane = tid & 63;
  int wv = tid >> 6;
  int l31 = lane & 31;
  int lh8 = (lane >> 5) * 8;

  bf16x8 afr[2][8];
#pragma unroll
  for (int i = 0; i < 2; ++i) {
    const u16* ap = Aqk_bf + ((2 * wv + i) * 32 + l31) * 128 + lh8;
#pragma unroll
    for (int s = 0; s < 8; ++s) afr[i][s] = ldfrag(ap + 16 * s);
  }

  {
    int mp = tid & 63;
    int tc = tid >> 6;
    const float* r0 = pattern + ((size_t)(b * M_ + 2 * mp)) * T_ + t0 + tc * 16;
    const float* r1 = r0 + T_;
    u32* xw = (u32*)sxs;
#pragma unroll
    for (int j = 0; j < 4; ++j) {
      float4 a = *(const float4*)(r0 + 4 * j);
      float4 bb = *(const float4*)(r1 + 4 * j);
      int tt = tc * 16 + 4 * j;
      xw[(tt + 0) * 68 + mp] = pk2(a.x, bb.x);
      xw[(tt + 1) * 68 + mp] = pk2(a.y, bb.y);
      xw[(tt + 2) * 68 + mp] = pk2(a.z, bb.z);
      xw[(tt + 3) * 68 + mp] = pk2(a.w, bb.w);
    }
  }
  __syncthreads();

#pragma unroll
  for (int tt = 0; tt < 2; ++tt) {
    bf16x8 bfr[8];
    const u16* bp = &sxs[(tt * 32 + l31) * XSTR + lh8];
#pragma unroll
    for (int s = 0; s < 8; ++s) bfr[s] = ldfrag(bp + 16 * s);
#pragma unroll
    for (int i = 0; i < 2; ++i) {
      f32x16 acc;
#pragma unroll
      for (int r = 0; r < 16; ++r) acc[r] = 0.f;
#pragma unroll
      for (int s = 0; s < 8; ++s)
        acc = __builtin_amdgcn_mfma_f32_32x32x16_bf16(afr[i][s], bfr[s], acc, 0, 0, 0);
      int ot = 2 * wv + i;
      u16* dst = (ot < 4) ? qT : kT;
      int ob = (ot & 3) * 32;
      size_t trow = ((size_t)(b * T_ + t0 + tt * 32 + l31)) * 128;
#pragma unroll
      for (int g = 0; g < 4; ++g) {
        int o0 = 8 * g + 4 * (lane >> 5);
        float v0 = acc[4 * g + 0] + cqk[ot * 32 + o0 + 0];
        float v1 = acc[4 * g + 1] + cqk[ot * 32 + o0 + 1];
        float v2 = acc[4 * g + 2] + cqk[ot * 32 + o0 + 2];
        float v3 = acc[4 * g + 3] + cqk[ot * 32 + o0 + 3];
        v0 = v0 > 0.f ? v0 : 0.01f * v0;
        v1 = v1 > 0.f ? v1 : 0.01f * v1;
        v2 = v2 > 0.f ? v2 : 0.01f * v2;
        v3 = v3 > 0.f ? v3 : 0.01f * v3;
        u32x2 w = {pk2(v0, v1), pk2(v2, v3)};
        *(u32x2*)(dst + trow + ob + o0) = w;
      }
    }
  }
}

// ---------------------------------------------------------------------------
// MFMA attention + fused o-MLP + rep_ex tail. LDS unioned to 53248 B -> 3 blk/CU.
#define QSTR 136
#define VSTR 72

__global__ __launch_bounds__(256, 3) void attn_mfma_kernel(
    const u16* __restrict__ qT, const u16* __restrict__ kT,
    const u16* __restrict__ vB, const u16* __restrict__ Ao_bf,
    const float* __restrict__ co, const float* __restrict__ Aofp,
    const float* __restrict__ meanv, float* __restrict__ out) {
  __shared__ alignas(16) u16 smem[26624];   // 53248 B
  u16* ks  = smem;            // [64][QSTR]
  u16* vs  = smem + 8704;     // [128][VSTR]; post-loop aliased as dls[2][64] f32
  u16* qsw = smem + 17920;    // [64][QSTR]: Q stage -> wsm[64][VSTR] -> P[64][QSTR]

  int b = blockIdx.y;
  int q0 = blockIdx.x * 64;
  int tid = threadIdx.x;
  int lane = tid & 63;
  int wv = tid >> 6;
  int l31 = lane & 31;
  int lh8 = (lane >> 5) * 8;

  // stage Q tile
  {
    const u16* gq = qT + (size_t)(b * T_ + q0) * 128;
#pragma unroll
    for (int it = 0; it < 4; ++it) {
      int r = it * 16 + (tid >> 4);
      int cm = (tid & 15) * 8;
      *(u32x4*)&qsw[r * QSTR + cm] = *(const u32x4*)&gq[r * 128 + cm];
    }
  }
  __syncthreads();

  int qw = (wv >> 1) * 32;
  int kw = (wv & 1) * 32;
  bf16x8 afrag[8];
  {
    const u16* qrow = &qsw[(qw + l31) * QSTR + lh8];
#pragma unroll
    for (int s = 0; s < 8; ++s) afrag[s] = ldfrag(qrow + s * 16);
  }

  int qt = wv & 1;
  int mb = (wv >> 1) * 2;

  f32x16 pacc[2];
  float dreg[16];
#pragma unroll
  for (int i = 0; i < 16; ++i) { pacc[0][i] = 0.f; pacc[1][i] = 0.f; dreg[i] = 0.f; }

  // register prefetch of K/V tile 0
  const u16* gkb = kT + (size_t)b * T_ * 128;
  const u16* gvb = vB + (size_t)b * M_ * T_;
  int kr = tid >> 4, kc = (tid & 15) * 8;
  int vr = tid >> 3, vc = (tid & 7) * 8;
  u32x4 kreg[4], vreg[4];
#pragma unroll
  for (int it = 0; it < 4; ++it) {
    kreg[it] = *(const u32x4*)&gkb[(size_t)(it * 16 + kr) * 128 + kc];
    vreg[it] = *(const u32x4*)&gvb[(size_t)(it * 32 + vr) * T_ + vc];
  }

  for (int kt = 0; kt < T_ / 64; ++kt) {
    int k0 = kt * 64;
    __syncthreads();  // prev PV (ks/vs/wsm readers) done
#pragma unroll
    for (int it = 0; it < 4; ++it) {
      *(u32x4*)&ks[(it * 16 + kr) * QSTR + kc] = kreg[it];
      *(u32x4*)&vs[(it * 32 + vr) * VSTR + vc] = vreg[it];
    }
    __syncthreads();

    // prefetch next tile (latency overlapped with S+exp+PV)
    {
      int kn = (kt < T_ / 64 - 1) ? k0 + 64 : k0;
#pragma unroll
      for (int it = 0; it < 4; ++it) {
        kreg[it] = *(const u32x4*)&gkb[(size_t)(kn + it * 16 + kr) * 128 + kc];
        vreg[it] = *(const u32x4*)&gvb[(size_t)(it * 32 + vr) * T_ + kn + vc];
      }
    }

    // S = Q^T K
    f32x16 sacc;
#pragma unroll
    for (int i = 0; i < 16; ++i) sacc[i] = 0.f;
    {
      const u16* krow = &ks[(kw + l31) * QSTR + lh8];
#pragma unroll
      for (int s = 0; s < 8; ++s) {
        bf16x8 bf = ldfrag(krow + s * 16);
        sacc = __builtin_amdgcn_mfma_f32_32x32x16_bf16(afrag[s], bf, sacc, 0, 0, 0);
      }
    }

    int kl = kw + l31;
    if (k0 == q0) {
#pragma unroll
      for (int r = 0; r < 16; ++r) {
        int qrow = qw + (r & 3) + 8 * (r >> 2) + 4 * (lane >> 5);
        if (qrow == kl) sacc[r] *= 0.97790291f;  // 1 - 1/sqrt(2048)
      }
    }
#pragma unroll
    for (int r = 0; r < 16; ++r) {
      int qrow = qw + (r & 3) + 8 * (r >> 2) + 4 * (lane >> 5);
      float w = __expf(__expf(sacc[r]));
      u16 wb = f2bf(w);
      dreg[r] += __uint_as_float((u32)wb << 16);
      qsw[qrow * VSTR + kl] = wb;   // wsm aliases Q-stage (Q already in regs)
    }
    __syncthreads();

    // PV: D[m][q] += V W^T
#pragma unroll
    for (int s2 = 0; s2 < 4; ++s2) {
      bf16x8 wf = ldfrag(&qsw[(qt * 32 + l31) * VSTR + s2 * 16 + lh8]);
#pragma unroll
      for (int mi = 0; mi < 2; ++mi) {
        bf16x8 vf = ldfrag(&vs[((mb + mi) * 32 + l31) * VSTR + s2 * 16 + lh8]);
        pacc[mi] = __builtin_amdgcn_mfma_f32_32x32x16_bf16(vf, wf, pacc[mi], 0, 0, 0);
      }
    }
  }
  __syncthreads();  // all PV done before dls aliases vs

  // denominator reduce
  float* dls = (float*)vs;  // [2][64]
#pragma unroll
  for (int r = 0; r < 16; ++r) {
    float d = dreg[r];
    for (int off = 1; off < 32; off <<= 1) d += __shfl_xor(d, off, 64);
    dreg[r] = d;
  }
  if (l31 == 0) {
#pragma unroll
    for (int r = 0; r < 16; ++r) {
      int qrow = qw + (r & 3) + 8 * (r >> 2) + 4 * (lane >> 5);
      dls[(wv & 1) * 64 + qrow] = dreg[r];
    }
  }
  __syncthreads();

  // P^T bf16 into qsw [q][m] (wsm dead)
  {
    int qcol = qt * 32 + l31;
    float rden = 1.f / (dls[qcol] + dls[64 + qcol]);
#pragma unroll
    for (int mi = 0; mi < 2; ++mi) {
      int mbase = (mb + mi) * 32 + 4 * (lane >> 5);
#pragma unroll
      for (int g = 0; g < 4; ++g) {
        float v0 = pacc[mi][4 * g + 0] * rden;
        float v1 = pacc[mi][4 * g + 1] * rden;
        float v2 = pacc[mi][4 * g + 2] * rden;
        float v3 = pacc[mi][4 * g + 3] * rden;
        u32x2 w = {pk2(v0, v1), pk2(v2, v3)};
        *(u32x2*)&qsw[qcol * QSTR + mbase + 8 * g] = w;
      }
    }
  }
  __syncthreads();

  // o-MLP epilogue (Ao frags loaded here to keep in-loop VGPR pressure down)
  bf16x8 aofr[8];
  {
    const u16* ap = Ao_bf + (wv * 32 + l31) * 128 + lh8;
#pragma unroll
    for (int s = 0; s < 8; ++s) aofr[s] = ldfrag(ap + 16 * s);
  }
#pragma unroll
  for (int qt2 = 0; qt2 < 2; ++qt2) {
    bf16x8 pfr[8];
    const u16* pp = &qsw[(qt2 * 32 + l31) * QSTR + lh8];
#pragma unroll
    for (int s = 0; s < 8; ++s) pfr[s] = ldfrag(pp + 16 * s);
    f32x16 oacc;
#pragma unroll
    for (int r = 0; r < 16; ++r) oacc[r] = 0.f;
#pragma unroll
    for (int s = 0; s < 8; ++s)
      oacc = __builtin_amdgcn_mfma_f32_32x32x16_bf16(aofr[s], pfr[s], oacc, 0, 0, 0);
#pragma unroll
    for (int r = 0; r < 16; ++r) {
      int orow = wv * 32 + (r & 3) + 8 * (r >> 2) + 4 * (lane >> 5);
      float v = oacc[r] + co[orow];
      v = v > 0.f ? v : 0.01f * v;
      out[((size_t)(b * M_ + orow)) * TOUT_ + q0 + qt2 * 32 + l31] = v;
    }
  }

  // rep_ex tail (one block-column per batch)
  if (q0 == 0 && tid < 128) {
    float acc = co[tid];
    const float* mv = meanv + b * 128;
    for (int m = 0; m < 128; ++m) acc = fmaf(Aofp[tid * 128 + m], mv[m], acc);
    acc = acc > 0.f ? acc : 0.01f * acc;
    out[((size_t)(b * M_ + tid)) * TOUT_ + 2048] = acc;
  }
}

// ---------------------------------------------------------------------------
extern "C" void kernel_launch(void* const* d_in, const int* in_sizes, int n_in,
                              void* d_out, int out_size, void* d_ws, size_t ws_size,
                              hipStream_t stream) {
  (void)in_sizes; (void)n_in; (void)out_size; (void)ws_size;
  const float* pattern = (const float*)d_in[0];
  const float* value   = (const float*)d_in[1];
  const float* Wq1 = (const float*)d_in[3];
  const float* bq1 = (const float*)d_in[4];
  const float* Wq2 = (const float*)d_in[5];
  const float* bq2 = (const float*)d_in[6];
  const float* Wk1 = (const float*)d_in[7];
  const float* bk1 = (const float*)d_in[8];
  const float* Wk2 = (const float*)d_in[9];
  const float* bk2 = (const float*)d_in[10];
  const float* Wo1 = (const float*)d_in[11];
  const float* bo1 = (const float*)d_in[12];
  const float* Wo2 = (const float*)d_in[13];
  const float* bo2 = (const float*)d_in[14];

  float* ws     = (float*)d_ws;
  float* A      = ws + A_OFF;
  float* c      = ws + C_OFF;
  float* meanv  = ws + MEAN_OFF;
  u16*   Aqk_bf = (u16*)(ws + AQKBF_OFF);
  u16*   Ao_bf  = (u16*)(ws + AOBF_OFF);
  u16*   qT     = (u16*)(ws + QT_OFF);
  u16*   kT     = (u16*)(ws + KT_OFF);
  u16*   vB     = (u16*)(ws + VB_OFF);
  float* out    = (float*)d_out;

  fuse_weights_all<<<384, 128, 0, stream>>>(
      Wq1, bq1, Wq2, bq2, Wk1, bk1, Wk2, bk2, Wo1, bo1, Wo2, bo2,
      A, c, Aqk_bf, Ao_bf);

  prep_kernel<<<512 + B_ * M_, 256, 0, stream>>>(
      pattern, Aqk_bf, c, qT, kT, value, vB, meanv);

  attn_mfma_kernel<<<dim3(T_ / 64, B_), 256, 0, stream>>>(
      qT, kT, vB, Ao_bf, c + 256, A + 32768, meanv, out);
}